// Round 1
// 420.787 us; speedup vs baseline: 1.1276x; 1.1276x over previous
//
#include <hip/hip_runtime.h>
#include <hip/hip_bf16.h>
#include <math.h>

#define CN 64
#define CG 128
#define CS 64
#define EPSV 1e-5f
#define ASTRIDE 28   // A row stride (27 taps + 1 pad, 16B-aligned)

#define BINW 512     // j-rows per bin
#define BINSH 9
#define BCAP 8192    // entry capacity per bin (avg ~6900, >14 sigma headroom)
#define ECH 4096     // entries per k_route block (16 rounds x 256)

__device__ __forceinline__ float4 ld4(const float* p){ return *(const float4*)p; }
__device__ __forceinline__ void st4(float* p, float4 v){ *(float4*)p = v; }

// ---------------- GEMM: Y = X[gather?] @ W, plus per-channel sum/sumsq ----------------
template<int CK, bool GATHER>
__global__ void __launch_bounds__(256) k_gemm(
    const float* __restrict__ X, const int* __restrict__ gidx,
    const float* __restrict__ W,
    float* __restrict__ Y, float* __restrict__ sum, float* __restrict__ sumsq, int Ng)
{
    __shared__ float Wl[CK*CN];      // 32 KB (CK=128) or 16 KB (CK=64)
    __shared__ float Xl[64*68];      // 17.4 KB, stride 68 floats
    int t = threadIdx.x;
    for (int idx = t; idx < CK*CN/4; idx += 256)
        ((float4*)Wl)[idx] = ((const float4*)W)[idx];

    int row0 = blockIdx.x * 64;
    int cg = t & 15, rg = t >> 4;
    int c0 = cg*4, r0 = rg*4;
    float4 acc[4];
    #pragma unroll
    for (int rr=0;rr<4;rr++) acc[rr] = make_float4(0.f,0.f,0.f,0.f);

    for (int kc = 0; kc < CK; kc += 64){
        for (int idx = t; idx < 64*16; idx += 256){
            int r = idx >> 4;
            int c4 = idx & 15;
            float4 v = make_float4(0.f,0.f,0.f,0.f);
            int row = row0 + r;
            if (row < Ng){
                int src = GATHER ? gidx[row] : row;
                v = ((const float4*)(X + (size_t)src*CK + kc))[c4];
            }
            *(float4*)&Xl[r*68 + c4*4] = v;
        }
        __syncthreads();
        for (int k = 0; k < 64; k += 4){
            float4 w0 = ld4(&Wl[(kc+k+0)*CN + c0]);
            float4 w1 = ld4(&Wl[(kc+k+1)*CN + c0]);
            float4 w2 = ld4(&Wl[(kc+k+2)*CN + c0]);
            float4 w3 = ld4(&Wl[(kc+k+3)*CN + c0]);
            #pragma unroll
            for (int rr=0;rr<4;rr++){
                float4 xv = ld4(&Xl[(r0+rr)*68 + k]);
                acc[rr].x = fmaf(xv.x,w0.x, fmaf(xv.y,w1.x, fmaf(xv.z,w2.x, fmaf(xv.w,w3.x, acc[rr].x))));
                acc[rr].y = fmaf(xv.x,w0.y, fmaf(xv.y,w1.y, fmaf(xv.z,w2.y, fmaf(xv.w,w3.y, acc[rr].y))));
                acc[rr].z = fmaf(xv.x,w0.z, fmaf(xv.y,w1.z, fmaf(xv.z,w2.z, fmaf(xv.w,w3.z, acc[rr].z))));
                acc[rr].w = fmaf(xv.x,w0.w, fmaf(xv.y,w1.w, fmaf(xv.z,w2.w, fmaf(xv.w,w3.w, acc[rr].w))));
            }
        }
        __syncthreads();
    }

    float4 s4 = make_float4(0.f,0.f,0.f,0.f), q4 = make_float4(0.f,0.f,0.f,0.f);
    #pragma unroll
    for (int rr=0;rr<4;rr++){
        int row = row0 + r0 + rr;
        if (row < Ng) st4(Y + (size_t)row*CN + c0, acc[rr]);
        s4.x += acc[rr].x; s4.y += acc[rr].y; s4.z += acc[rr].z; s4.w += acc[rr].w;
        q4.x += acc[rr].x*acc[rr].x; q4.y += acc[rr].y*acc[rr].y;
        q4.z += acc[rr].z*acc[rr].z; q4.w += acc[rr].w*acc[rr].w;
    }
    float* red = Xl;
    __syncthreads();
    st4(red + rg*64 + c0, s4);
    st4(red + 1024 + rg*64 + c0, q4);
    __syncthreads();
    if (t < 64){
        float ss = 0.f, qq = 0.f;
        #pragma unroll
        for (int r=0;r<16;r++){ ss += red[r*64 + t]; qq += red[1024 + r*64 + t]; }
        atomicAdd(&sum[t], ss); atomicAdd(&sumsq[t], qq);
    }
}

__device__ __forceinline__ void bnparams(float4 s, float4 q, float4 gam, float4 bet,
                                         float invN, float4& scl, float4& sft)
{
    float mux = s.x*invN, muy = s.y*invN, muz = s.z*invN, muw = s.w*invN;
    float vx = q.x*invN - mux*mux, vy = q.y*invN - muy*muy;
    float vz = q.z*invN - muz*muz, vw = q.w*invN - muw*muw;
    scl = make_float4(gam.x*rsqrtf(vx+EPSV), gam.y*rsqrtf(vy+EPSV),
                      gam.z*rsqrtf(vz+EPSV), gam.w*rsqrtf(vw+EPSV));
    sft = make_float4(bet.x - mux*scl.x, bet.y - muy*scl.y,
                      bet.z - muz*scl.z, bet.w - muw*scl.w);
}

// --------- fuse: w[i] = relu(relu(BN(Yg)) + relu(BN(Ys))) @ Wc, plus w sum/sumsq ---------
__global__ void __launch_bounds__(256) k_fuse(
    const float* __restrict__ Yg, const float* __restrict__ Ys,
    const float* __restrict__ stats,
    const float* __restrict__ gamma_g, const float* __restrict__ beta_g,
    const float* __restrict__ gamma_s, const float* __restrict__ beta_s,
    const float* __restrict__ Wc,
    float* __restrict__ w, float* __restrict__ sum_w, float* __restrict__ sumsq_w, int Ng)
{
    int t = threadIdx.x; int l = t & 15; int r = t >> 4;
    int i = blockIdx.x*16 + r;
    int c4 = l*4;
    float invN = 1.0f/(float)Ng;
    float4 sclg, sftg, scls, sfts;
    bnparams(ld4(stats + c4),       ld4(stats + 64 + c4),  ld4(gamma_g + c4), ld4(beta_g + c4), invN, sclg, sftg);
    bnparams(ld4(stats + 128 + c4), ld4(stats + 192 + c4), ld4(gamma_s + c4), ld4(beta_s + c4), invN, scls, sfts);
    float partial = 0.f;
    if (i < Ng){
        float4 a = ld4(Yg + (size_t)i*CN + c4);
        float4 b = ld4(Ys + (size_t)i*CN + c4);
        float ax = fmaxf(0.f, fmaf(a.x, sclg.x, sftg.x));
        float ay = fmaxf(0.f, fmaf(a.y, sclg.y, sftg.y));
        float az = fmaxf(0.f, fmaf(a.z, sclg.z, sftg.z));
        float aw = fmaxf(0.f, fmaf(a.w, sclg.w, sftg.w));
        float bx = fmaxf(0.f, fmaf(b.x, scls.x, sfts.x));
        float by = fmaxf(0.f, fmaf(b.y, scls.y, sfts.y));
        float bz = fmaxf(0.f, fmaf(b.z, scls.z, sfts.z));
        float bw = fmaxf(0.f, fmaf(b.w, scls.w, sfts.w));
        float sx = fmaxf(0.f, ax+bx), sy = fmaxf(0.f, ay+by);
        float sz = fmaxf(0.f, az+bz), sw = fmaxf(0.f, aw+bw);
        float4 wc = ld4(Wc + c4);
        partial = sx*wc.x + sy*wc.y + sz*wc.z + sw*wc.w;
    }
    partial += __shfl_xor(partial, 1);
    partial += __shfl_xor(partial, 2);
    partial += __shfl_xor(partial, 4);
    partial += __shfl_xor(partial, 8);
    __shared__ float red[32];
    if (l == 0){
        if (i < Ng) w[i] = partial;
        red[r] = (i < Ng) ? partial : 0.f;
        red[16+r] = (i < Ng) ? partial*partial : 0.f;
    }
    __syncthreads();
    if (t == 0){
        float s2=0.f,q2=0.f;
        #pragma unroll
        for (int j2=0;j2<16;j2++){ s2+=red[j2]; q2+=red[16+j2]; }
        atomicAdd(sum_w, s2); atomicAdd(sumsq_w, q2);
    }
}

// --------- route: bin the 2.7M (att,j,k) entries by j>>9 into staging, LDS-aggregated tickets ---------
// Replaces 2.7M device-scope atomics with ~130K ticket atomics + coalesced streaming writes.
__global__ void __launch_bounds__(256) k_route(
    const int* __restrict__ pin, const int* __restrict__ pout,
    const float* __restrict__ w, const float* __restrict__ stats,
    const float* __restrict__ gamma_c, const float* __restrict__ beta_c,
    unsigned int* __restrict__ gcount, uint2* __restrict__ staging,
    int E, int P, int NB, int Ng)
{
    __shared__ unsigned int hist[512];
    __shared__ unsigned int gbase[512];
    __shared__ unsigned int lbase[512];
    __shared__ unsigned int rank2[512];
    __shared__ unsigned int scn[2][512];
    __shared__ int s_e[ECH];
    __shared__ unsigned int s_dst[ECH];

    int t = threadIdx.x;
    for (int b = t; b < 512; b += 256){ hist[b] = 0u; rank2[b] = 0u; }
    __syncthreads();

    int e0 = blockIdx.x * ECH;

    // pass A: per-block histogram of bins
    #pragma unroll
    for (int r = 0; r < ECH/256; ++r){
        int e = e0 + r*256 + t;
        if (e < E){
            int j = pout[e];
            atomicAdd(&hist[j >> BINSH], 1u);
        }
    }
    __syncthreads();

    // global tickets: one atomic per non-empty (block,bin)
    for (int b = t; b < 512; b += 256){
        unsigned h = hist[b];
        gbase[b] = (h != 0u && b < NB) ? atomicAdd(&gcount[b], h) : 0u;
        scn[0][b] = h;
    }
    __syncthreads();

    // Hillis-Steele inclusive scan over 512 bins (ping-pong)
    int src = 0;
    for (int off = 1; off < 512; off <<= 1){
        for (int i = t; i < 512; i += 256){
            unsigned v = scn[src][i];
            if (i >= off) v += scn[src][i-off];
            scn[src^1][i] = v;
        }
        __syncthreads();
        src ^= 1;
    }
    for (int b = t; b < 512; b += 256) lbase[b] = scn[src][b] - hist[b];
    __syncthreads();

    // pass B: assign slots (LDS-ordered by bin) + global destinations
    #pragma unroll
    for (int r = 0; r < ECH/256; ++r){
        int e = e0 + r*256 + t;
        if (e < E){
            int j = pout[e];
            int b = j >> BINSH;
            unsigned rk = atomicAdd(&rank2[b], 1u);
            unsigned slot = lbase[b] + rk;
            unsigned dst = gbase[b] + rk;
            if (dst < BCAP){
                s_e[slot] = e;
                s_dst[slot] = (unsigned)b*BCAP + dst;
            } else {
                s_e[slot] = -1;   // statistically impossible overflow: drop
            }
        }
    }
    __syncthreads();

    // pass C: compute att, flush LDS-ordered entries -> coalesced runs per bin
    int nval = min(ECH, E - e0);
    float invN = 1.0f/(float)Ng;
    float mu = stats[256]*invN;
    float var = stats[257]*invN - mu*mu;
    float sc = gamma_c[0]*rsqrtf(var+EPSV);
    float sh = beta_c[0] - mu*sc;
    for (int idx = t; idx < nval; idx += 256){
        int e = s_e[idx];
        if (e < 0) continue;
        int i = pin[e];
        int j = pout[e];
        int k = e / P;
        float z = fmaf(sc, w[i], sh);
        float att = 1.0f/(1.0f+__expf(-z));
        unsigned meta = ((unsigned)(j & (BINW-1)) << 5) | (unsigned)k;
        staging[s_dst[idx]] = make_uint2(__float_as_uint(att), meta);
    }
}

// --------- binacc: one block per bin; LDS atomic accumulate; dense coalesced A write ---------
// Writes every (j,k) cell of its bin -> also replaces the 22.4MB memset of A.
__global__ void __launch_bounds__(256) k_binacc(
    const unsigned int* __restrict__ gcount, const uint2* __restrict__ staging,
    float* __restrict__ A, int Nx)
{
    __shared__ float Ab[BINW*ASTRIDE];   // 512*28*4 = 57344 B
    int t = threadIdx.x;
    int b = blockIdx.x;
    for (int i = t; i < BINW*ASTRIDE; i += 256) Ab[i] = 0.f;
    __syncthreads();

    unsigned n = gcount[b]; if (n > BCAP) n = BCAP;
    const uint2* sp = staging + (size_t)b*BCAP;
    for (unsigned idx = t; idx < n; idx += 256){
        uint2 ent = sp[idx];
        float att = __uint_as_float(ent.x);
        unsigned meta = ent.y;
        atomicAdd(&Ab[(meta >> 5)*ASTRIDE + (meta & 31u)], att);
    }
    __syncthreads();

    int j0 = b * BINW;
    int rows = min(BINW, Nx - j0);
    if (rows <= 0) return;
    const float4* srcp = (const float4*)Ab;
    float4* dstp = (float4*)(A + (size_t)j0*ASTRIDE);
    int n4 = rows * (ASTRIDE/4);
    for (int i = t; i < n4; i += 256) dstp[i] = srcp[i];
}

// --------- final: out[j,:] = x[j,:] * (b_inv + sum_k A[j][k] * W_inv[k,:]) ---------
__global__ void __launch_bounds__(256) k_final(
    const float* __restrict__ x, const float* __restrict__ A,
    const float* __restrict__ Winv, const float* __restrict__ binv,
    float* __restrict__ out, int Nx, int K)
{
    __shared__ float Wl[27*64];      // 6.75 KB  [k][c]
    __shared__ float bl[64];
    __shared__ float Al[64*36];      // 9.2 KB, stride 36 (16B-aligned, conflict-safe)
    int t = threadIdx.x;
    for (int idx = t; idx < 27*64/4; idx += 256)
        ((float4*)Wl)[idx] = ((const float4*)Winv)[idx];
    if (t < 64) bl[t] = binv[t];
    int j0 = blockIdx.x * 64;
    for (int idx = t; idx < 64*(ASTRIDE/4); idx += 256){
        int r = idx / (ASTRIDE/4);
        int c4 = idx % (ASTRIDE/4);
        float4 v = make_float4(0.f,0.f,0.f,0.f);
        if (j0 + r < Nx) v = ld4(A + (size_t)(j0+r)*ASTRIDE + c4*4);
        st4(&Al[r*36 + c4*4], v);
    }
    __syncthreads();

    int cc = (t & 15) * 4;
    int jb = t >> 4;
    float4 acc[4];
    float4 b4 = ld4(&bl[cc]);
    #pragma unroll
    for (int q=0;q<4;q++) acc[q] = b4;
    for (int k=0;k<K;k++){
        float4 wv = ld4(&Wl[k*64 + cc]);
        #pragma unroll
        for (int q=0;q<4;q++){
            float a = Al[(q*16 + jb)*36 + k];
            acc[q].x = fmaf(a, wv.x, acc[q].x);
            acc[q].y = fmaf(a, wv.y, acc[q].y);
            acc[q].z = fmaf(a, wv.z, acc[q].z);
            acc[q].w = fmaf(a, wv.w, acc[q].w);
        }
    }
    #pragma unroll
    for (int q=0;q<4;q++){
        int j = j0 + q*16 + jb;
        if (j < Nx){
            float4 xv = ld4(x + (size_t)j*CS + cc);
            st4(out + (size_t)j*CS + cc,
                make_float4(xv.x*acc[q].x, xv.y*acc[q].y, xv.z*acc[q].z, xv.w*acc[q].w));
        }
    }
}

extern "C" void kernel_launch(void* const* d_in, const int* in_sizes, int n_in,
                              void* d_out, int out_size, void* d_ws, size_t ws_size,
                              hipStream_t stream)
{
    const float* g        = (const float*)d_in[0];
    const float* x        = (const float*)d_in[1];
    const int*   down_idx = (const int*)d_in[2];
    const int*   pin      = (const int*)d_in[3];
    const int*   pout     = (const int*)d_in[4];
    const float* Wg       = (const float*)d_in[5];
    const float* Ws       = (const float*)d_in[6];
    const float* Wc       = (const float*)d_in[7];
    const float* Winv     = (const float*)d_in[8];
    const float* binv     = (const float*)d_in[9];
    const float* gamma_g  = (const float*)d_in[10];
    const float* beta_g   = (const float*)d_in[11];
    const float* gamma_s  = (const float*)d_in[12];
    const float* beta_s   = (const float*)d_in[13];
    const float* gamma_c  = (const float*)d_in[14];
    const float* beta_c   = (const float*)d_in[15];

    int Ng = in_sizes[0] / CG;       // 60000
    int Nx = in_sizes[1] / CS;       // 200000
    int K  = in_sizes[8] / CS;       // 27
    int P  = in_sizes[3] / K;        // 100000
    int E  = K * P;                  // 2.7M
    int NB = (Nx + BINW - 1) >> BINSH; // 391 bins

    float* ws = (float*)d_ws;
    size_t offA     = 0;
    size_t offStats = (size_t)Nx * ASTRIDE;    // A: Nx*28 floats
    size_t offYg    = offStats + 1024;         // stats 512 + gcount 512
    size_t offYs    = offYg + (size_t)Ng*CN;
    size_t offW     = offYs + (size_t)Ng*CN;
    size_t offStag  = offW + (size_t)Ng;       // staging: NB*BCAP uint2

    float* A      = ws + offA;
    float* stats  = ws + offStats;
    unsigned int* gcount = (unsigned int*)(ws + offStats + 512);
    float* Yg     = ws + offYg;
    float* Ys     = ws + offYs;
    float* wbuf   = ws + offW;
    uint2* staging = (uint2*)(ws + offStag);

    // zero only stats + bin counters (A is fully overwritten by k_binacc now)
    hipMemsetAsync(stats, 0, 1024 * sizeof(float), stream);

    int gb = (Ng + 63) / 64;
    k_gemm<CG,false><<<gb, 256, 0, stream>>>(g, nullptr, Wg, Yg, stats+0, stats+64, Ng);
    k_gemm<CS,true ><<<gb, 256, 0, stream>>>(x, down_idx, Ws, Ys, stats+128, stats+192, Ng);
    k_fuse<<<(Ng+15)/16, 256, 0, stream>>>(Yg, Ys, stats, gamma_g, beta_g,
                                           gamma_s, beta_s, Wc, wbuf,
                                           stats+256, stats+257, Ng);
    int rb = (E + ECH - 1) / ECH;
    k_route<<<rb, 256, 0, stream>>>(pin, pout, wbuf, stats, gamma_c, beta_c,
                                    gcount, staging, E, P, NB, Ng);
    k_binacc<<<NB, 256, 0, stream>>>(gcount, staging, A, Nx);
    k_final<<<(Nx+63)/64, 256, 0, stream>>>(x, A, Winv, binv, (float*)d_out, Nx, K);
}

// Round 2
// 335.751 us; speedup vs baseline: 1.4131x; 1.2533x over previous
//
#include <hip/hip_runtime.h>
#include <hip/hip_bf16.h>
#include <math.h>

#define CN 64
#define CG 128
#define CS 64
#define EPSV 1e-5f
#define ASTRIDE 28   // A row stride (27 taps + 1 pad, 16B-aligned)

#define BINW 512     // j-rows per bin
#define BINSH 9
#define BCAP 8192    // entry capacity per bin (avg ~6900, >14 sigma headroom)
#define ECH 4096     // entries per k_route block (16 rounds x 256)
#define FROWS 64     // rows per k_fuse block

__device__ __forceinline__ float4 ld4(const float* p){ return *(const float4*)p; }
__device__ __forceinline__ void st4(float* p, float4 v){ *(float4*)p = v; }

// ---------------- GEMM: Y = X[gather?] @ W, plus per-channel sum/sumsq ----------------
template<int CK, bool GATHER>
__global__ void __launch_bounds__(256) k_gemm(
    const float* __restrict__ X, const int* __restrict__ gidx,
    const float* __restrict__ W,
    float* __restrict__ Y, float* __restrict__ sum, float* __restrict__ sumsq, int Ng)
{
    __shared__ float Wl[CK*CN];      // 32 KB (CK=128) or 16 KB (CK=64)
    __shared__ float Xl[64*68];      // 17.4 KB, stride 68 floats
    int t = threadIdx.x;
    for (int idx = t; idx < CK*CN/4; idx += 256)
        ((float4*)Wl)[idx] = ((const float4*)W)[idx];

    int row0 = blockIdx.x * 64;
    int cg = t & 15, rg = t >> 4;
    int c0 = cg*4, r0 = rg*4;
    float4 acc[4];
    #pragma unroll
    for (int rr=0;rr<4;rr++) acc[rr] = make_float4(0.f,0.f,0.f,0.f);

    for (int kc = 0; kc < CK; kc += 64){
        for (int idx = t; idx < 64*16; idx += 256){
            int r = idx >> 4;
            int c4 = idx & 15;
            float4 v = make_float4(0.f,0.f,0.f,0.f);
            int row = row0 + r;
            if (row < Ng){
                int src = GATHER ? gidx[row] : row;
                v = ((const float4*)(X + (size_t)src*CK + kc))[c4];
            }
            *(float4*)&Xl[r*68 + c4*4] = v;
        }
        __syncthreads();
        for (int k = 0; k < 64; k += 4){
            float4 w0 = ld4(&Wl[(kc+k+0)*CN + c0]);
            float4 w1 = ld4(&Wl[(kc+k+1)*CN + c0]);
            float4 w2 = ld4(&Wl[(kc+k+2)*CN + c0]);
            float4 w3 = ld4(&Wl[(kc+k+3)*CN + c0]);
            #pragma unroll
            for (int rr=0;rr<4;rr++){
                float4 xv = ld4(&Xl[(r0+rr)*68 + k]);
                acc[rr].x = fmaf(xv.x,w0.x, fmaf(xv.y,w1.x, fmaf(xv.z,w2.x, fmaf(xv.w,w3.x, acc[rr].x))));
                acc[rr].y = fmaf(xv.x,w0.y, fmaf(xv.y,w1.y, fmaf(xv.z,w2.y, fmaf(xv.w,w3.y, acc[rr].y))));
                acc[rr].z = fmaf(xv.x,w0.z, fmaf(xv.y,w1.z, fmaf(xv.z,w2.z, fmaf(xv.w,w3.z, acc[rr].z))));
                acc[rr].w = fmaf(xv.x,w0.w, fmaf(xv.y,w1.w, fmaf(xv.z,w2.w, fmaf(xv.w,w3.w, acc[rr].w))));
            }
        }
        __syncthreads();
    }

    float4 s4 = make_float4(0.f,0.f,0.f,0.f), q4 = make_float4(0.f,0.f,0.f,0.f);
    #pragma unroll
    for (int rr=0;rr<4;rr++){
        int row = row0 + r0 + rr;
        if (row < Ng) st4(Y + (size_t)row*CN + c0, acc[rr]);
        s4.x += acc[rr].x; s4.y += acc[rr].y; s4.z += acc[rr].z; s4.w += acc[rr].w;
        q4.x += acc[rr].x*acc[rr].x; q4.y += acc[rr].y*acc[rr].y;
        q4.z += acc[rr].z*acc[rr].z; q4.w += acc[rr].w*acc[rr].w;
    }
    float* red = Xl;
    __syncthreads();
    st4(red + rg*64 + c0, s4);
    st4(red + 1024 + rg*64 + c0, q4);
    __syncthreads();
    if (t < 64){
        float ss = 0.f, qq = 0.f;
        #pragma unroll
        for (int r=0;r<16;r++){ ss += red[r*64 + t]; qq += red[1024 + r*64 + t]; }
        atomicAdd(&sum[t], ss); atomicAdd(&sumsq[t], qq);
    }
}

__device__ __forceinline__ void bnparams(float4 s, float4 q, float4 gam, float4 bet,
                                         float invN, float4& scl, float4& sft)
{
    float mux = s.x*invN, muy = s.y*invN, muz = s.z*invN, muw = s.w*invN;
    float vx = q.x*invN - mux*mux, vy = q.y*invN - muy*muy;
    float vz = q.z*invN - muz*muz, vw = q.w*invN - muw*muw;
    scl = make_float4(gam.x*rsqrtf(vx+EPSV), gam.y*rsqrtf(vy+EPSV),
                      gam.z*rsqrtf(vz+EPSV), gam.w*rsqrtf(vw+EPSV));
    sft = make_float4(bet.x - mux*scl.x, bet.y - muy*scl.y,
                      bet.z - muz*scl.z, bet.w - muw*scl.w);
}

// --------- fuse: w[i] = relu(relu(BN(Yg)) + relu(BN(Ys))) @ Wc; per-block partial sum/sumsq ---------
// NO global atomics: 938 blocks each write one (sum, sumsq) pair; k_route reduces them.
__global__ void __launch_bounds__(256) k_fuse(
    const float* __restrict__ Yg, const float* __restrict__ Ys,
    const float* __restrict__ stats,
    const float* __restrict__ gamma_g, const float* __restrict__ beta_g,
    const float* __restrict__ gamma_s, const float* __restrict__ beta_s,
    const float* __restrict__ Wc,
    float* __restrict__ w, float* __restrict__ wpart, int Ng)
{
    int t = threadIdx.x; int l = t & 15; int r = t >> 4;
    int c4 = l*4;
    float invN = 1.0f/(float)Ng;
    float4 sclg, sftg, scls, sfts;
    bnparams(ld4(stats + c4),       ld4(stats + 64 + c4),  ld4(gamma_g + c4), ld4(beta_g + c4), invN, sclg, sftg);
    bnparams(ld4(stats + 128 + c4), ld4(stats + 192 + c4), ld4(gamma_s + c4), ld4(beta_s + c4), invN, scls, sfts);
    float4 wc = ld4(Wc + c4);

    int base = blockIdx.x * FROWS;
    float s_acc = 0.f, q_acc = 0.f;
    #pragma unroll
    for (int rr = 0; rr < FROWS/16; ++rr){
        int i = base + rr*16 + r;
        float partial = 0.f;
        if (i < Ng){
            float4 a = ld4(Yg + (size_t)i*CN + c4);
            float4 b = ld4(Ys + (size_t)i*CN + c4);
            float ax = fmaxf(0.f, fmaf(a.x, sclg.x, sftg.x));
            float ay = fmaxf(0.f, fmaf(a.y, sclg.y, sftg.y));
            float az = fmaxf(0.f, fmaf(a.z, sclg.z, sftg.z));
            float aw = fmaxf(0.f, fmaf(a.w, sclg.w, sftg.w));
            float bx = fmaxf(0.f, fmaf(b.x, scls.x, sfts.x));
            float by = fmaxf(0.f, fmaf(b.y, scls.y, sfts.y));
            float bz = fmaxf(0.f, fmaf(b.z, scls.z, sfts.z));
            float bw = fmaxf(0.f, fmaf(b.w, scls.w, sfts.w));
            float sx = fmaxf(0.f, ax+bx), sy = fmaxf(0.f, ay+by);
            float sz = fmaxf(0.f, az+bz), sw = fmaxf(0.f, aw+bw);
            partial = sx*wc.x + sy*wc.y + sz*wc.z + sw*wc.w;
        }
        partial += __shfl_xor(partial, 1);
        partial += __shfl_xor(partial, 2);
        partial += __shfl_xor(partial, 4);
        partial += __shfl_xor(partial, 8);
        if (l == 0){
            if (i < Ng) w[i] = partial;
            s_acc += partial;               // partial==0 for i>=Ng
            q_acc += partial*partial;
        }
    }
    __shared__ float red[32];
    if (l == 0){ red[r] = s_acc; red[16+r] = q_acc; }
    __syncthreads();
    if (t == 0){
        float s2=0.f,q2=0.f;
        #pragma unroll
        for (int j2=0;j2<16;j2++){ s2+=red[j2]; q2+=red[16+j2]; }
        wpart[2*blockIdx.x]   = s2;
        wpart[2*blockIdx.x+1] = q2;
    }
}

// --------- route: bin the 2.7M (att,j,k) entries by j>>9 into staging, LDS-aggregated tickets ---------
__global__ void __launch_bounds__(256) k_route(
    const int* __restrict__ pin, const int* __restrict__ pout,
    const float* __restrict__ w, const float* __restrict__ wpart, int nf,
    const float* __restrict__ gamma_c, const float* __restrict__ beta_c,
    unsigned int* __restrict__ gcount, uint2* __restrict__ staging,
    int E, int P, int NB, int Ng)
{
    __shared__ unsigned int hist[512];
    __shared__ unsigned int gbase[512];
    __shared__ unsigned int lbase[512];
    __shared__ unsigned int rank2[512];
    __shared__ unsigned int scn[2][512];
    __shared__ int s_e[ECH];
    __shared__ unsigned int s_dst[ECH];
    __shared__ float r8[8];

    int t = threadIdx.x;
    for (int b = t; b < 512; b += 256){ hist[b] = 0u; rank2[b] = 0u; }

    // reduce k_fuse partials -> w mean/var (L2-resident, ~7.5 KB)
    float ls = 0.f, lq = 0.f;
    for (int idx = t; idx < nf; idx += 256){ ls += wpart[2*idx]; lq += wpart[2*idx+1]; }
    #pragma unroll
    for (int off = 1; off < 64; off <<= 1){
        ls += __shfl_xor(ls, off);
        lq += __shfl_xor(lq, off);
    }
    if ((t & 63) == 0){ r8[t>>6] = ls; r8[4 + (t>>6)] = lq; }
    __syncthreads();
    float S = r8[0]+r8[1]+r8[2]+r8[3];
    float Q = r8[4]+r8[5]+r8[6]+r8[7];
    float invN = 1.0f/(float)Ng;
    float mu = S*invN;
    float var = Q*invN - mu*mu;
    float sc = gamma_c[0]*rsqrtf(var+EPSV);
    float sh = beta_c[0] - mu*sc;

    int e0 = blockIdx.x * ECH;

    // pass A: per-block histogram of bins
    #pragma unroll
    for (int r = 0; r < ECH/256; ++r){
        int e = e0 + r*256 + t;
        if (e < E){
            int j = pout[e];
            atomicAdd(&hist[j >> BINSH], 1u);
        }
    }
    __syncthreads();

    // global tickets: one atomic per non-empty (block,bin)
    for (int b = t; b < 512; b += 256){
        unsigned h = hist[b];
        gbase[b] = (h != 0u && b < NB) ? atomicAdd(&gcount[b], h) : 0u;
        scn[0][b] = h;
    }
    __syncthreads();

    // Hillis-Steele inclusive scan over 512 bins (ping-pong)
    int src = 0;
    for (int off = 1; off < 512; off <<= 1){
        for (int i = t; i < 512; i += 256){
            unsigned v = scn[src][i];
            if (i >= off) v += scn[src][i-off];
            scn[src^1][i] = v;
        }
        __syncthreads();
        src ^= 1;
    }
    for (int b = t; b < 512; b += 256) lbase[b] = scn[src][b] - hist[b];
    __syncthreads();

    // pass B: assign slots (LDS-ordered by bin) + global destinations
    #pragma unroll
    for (int r = 0; r < ECH/256; ++r){
        int e = e0 + r*256 + t;
        if (e < E){
            int j = pout[e];
            int b = j >> BINSH;
            unsigned rk = atomicAdd(&rank2[b], 1u);
            unsigned slot = lbase[b] + rk;
            unsigned dst = gbase[b] + rk;
            if (dst < BCAP){
                s_e[slot] = e;
                s_dst[slot] = (unsigned)b*BCAP + dst;
            } else {
                s_e[slot] = -1;   // statistically impossible overflow: drop
            }
        }
    }
    __syncthreads();

    // pass C: compute att, flush LDS-ordered entries -> coalesced runs per bin
    int nval = min(ECH, E - e0);
    for (int idx = t; idx < nval; idx += 256){
        int e = s_e[idx];
        if (e < 0) continue;
        int i = pin[e];
        int j = pout[e];
        int k = e / P;
        float z = fmaf(sc, w[i], sh);
        float att = 1.0f/(1.0f+__expf(-z));
        unsigned meta = ((unsigned)(j & (BINW-1)) << 5) | (unsigned)k;
        staging[s_dst[idx]] = make_uint2(__float_as_uint(att), meta);
    }
}

// --------- binacc: one block per bin; LDS atomic accumulate; dense coalesced A write ---------
__global__ void __launch_bounds__(256) k_binacc(
    const unsigned int* __restrict__ gcount, const uint2* __restrict__ staging,
    float* __restrict__ A, int Nx)
{
    __shared__ float Ab[BINW*ASTRIDE];   // 512*28*4 = 57344 B
    int t = threadIdx.x;
    int b = blockIdx.x;
    for (int i = t; i < BINW*ASTRIDE; i += 256) Ab[i] = 0.f;
    __syncthreads();

    unsigned n = gcount[b]; if (n > BCAP) n = BCAP;
    const uint2* sp = staging + (size_t)b*BCAP;
    for (unsigned idx = t; idx < n; idx += 256){
        uint2 ent = sp[idx];
        float att = __uint_as_float(ent.x);
        unsigned meta = ent.y;
        atomicAdd(&Ab[(meta >> 5)*ASTRIDE + (meta & 31u)], att);
    }
    __syncthreads();

    int j0 = b * BINW;
    int rows = min(BINW, Nx - j0);
    if (rows <= 0) return;
    const float4* srcp = (const float4*)Ab;
    float4* dstp = (float4*)(A + (size_t)j0*ASTRIDE);
    int n4 = rows * (ASTRIDE/4);
    for (int i = t; i < n4; i += 256) dstp[i] = srcp[i];
}

// --------- final: out[j,:] = x[j,:] * (b_inv + sum_k A[j][k] * W_inv[k,:]) ---------
__global__ void __launch_bounds__(256) k_final(
    const float* __restrict__ x, const float* __restrict__ A,
    const float* __restrict__ Winv, const float* __restrict__ binv,
    float* __restrict__ out, int Nx, int K)
{
    __shared__ float Wl[27*64];      // 6.75 KB  [k][c]
    __shared__ float bl[64];
    __shared__ float Al[64*36];      // 9.2 KB, stride 36 (16B-aligned, conflict-safe)
    int t = threadIdx.x;
    for (int idx = t; idx < 27*64/4; idx += 256)
        ((float4*)Wl)[idx] = ((const float4*)Winv)[idx];
    if (t < 64) bl[t] = binv[t];
    int j0 = blockIdx.x * 64;
    for (int idx = t; idx < 64*(ASTRIDE/4); idx += 256){
        int r = idx / (ASTRIDE/4);
        int c4 = idx % (ASTRIDE/4);
        float4 v = make_float4(0.f,0.f,0.f,0.f);
        if (j0 + r < Nx) v = ld4(A + (size_t)(j0+r)*ASTRIDE + c4*4);
        st4(&Al[r*36 + c4*4], v);
    }
    __syncthreads();

    int cc = (t & 15) * 4;
    int jb = t >> 4;
    float4 acc[4];
    float4 b4 = ld4(&bl[cc]);
    #pragma unroll
    for (int q=0;q<4;q++) acc[q] = b4;
    for (int k=0;k<K;k++){
        float4 wv = ld4(&Wl[k*64 + cc]);
        #pragma unroll
        for (int q=0;q<4;q++){
            float a = Al[(q*16 + jb)*36 + k];
            acc[q].x = fmaf(a, wv.x, acc[q].x);
            acc[q].y = fmaf(a, wv.y, acc[q].y);
            acc[q].z = fmaf(a, wv.z, acc[q].z);
            acc[q].w = fmaf(a, wv.w, acc[q].w);
        }
    }
    #pragma unroll
    for (int q=0;q<4;q++){
        int j = j0 + q*16 + jb;
        if (j < Nx){
            float4 xv = ld4(x + (size_t)j*CS + cc);
            st4(out + (size_t)j*CS + cc,
                make_float4(xv.x*acc[q].x, xv.y*acc[q].y, xv.z*acc[q].z, xv.w*acc[q].w));
        }
    }
}

extern "C" void kernel_launch(void* const* d_in, const int* in_sizes, int n_in,
                              void* d_out, int out_size, void* d_ws, size_t ws_size,
                              hipStream_t stream)
{
    const float* g        = (const float*)d_in[0];
    const float* x        = (const float*)d_in[1];
    const int*   down_idx = (const int*)d_in[2];
    const int*   pin      = (const int*)d_in[3];
    const int*   pout     = (const int*)d_in[4];
    const float* Wg       = (const float*)d_in[5];
    const float* Ws       = (const float*)d_in[6];
    const float* Wc       = (const float*)d_in[7];
    const float* Winv     = (const float*)d_in[8];
    const float* binv     = (const float*)d_in[9];
    const float* gamma_g  = (const float*)d_in[10];
    const float* beta_g   = (const float*)d_in[11];
    const float* gamma_s  = (const float*)d_in[12];
    const float* beta_s   = (const float*)d_in[13];
    const float* gamma_c  = (const float*)d_in[14];
    const float* beta_c   = (const float*)d_in[15];

    int Ng = in_sizes[0] / CG;       // 60000
    int Nx = in_sizes[1] / CS;       // 200000
    int K  = in_sizes[8] / CS;       // 27
    int P  = in_sizes[3] / K;        // 100000
    int E  = K * P;                  // 2.7M
    int NB = (Nx + BINW - 1) >> BINSH; // 391 bins
    int fb = (Ng + FROWS - 1) / FROWS; // 938 fuse blocks

    float* ws = (float*)d_ws;
    size_t offA     = 0;
    size_t offStats = (size_t)Nx * ASTRIDE;    // A: Nx*28 floats
    size_t offWp    = offStats + 1024;         // stats 512 + gcount 512
    size_t offYg    = offWp + 2048;            // wpart: 2*fb floats (<=2048)
    size_t offYs    = offYg + (size_t)Ng*CN;
    size_t offW     = offYs + (size_t)Ng*CN;
    size_t offStag  = offW + (size_t)Ng;       // staging: NB*BCAP uint2

    float* A      = ws + offA;
    float* stats  = ws + offStats;
    unsigned int* gcount = (unsigned int*)(ws + offStats + 512);
    float* wpart  = ws + offWp;
    float* Yg     = ws + offYg;
    float* Ys     = ws + offYs;
    float* wbuf   = ws + offW;
    uint2* staging = (uint2*)(ws + offStag);

    // zero only gemm stats + bin counters
    hipMemsetAsync(stats, 0, 1024 * sizeof(float), stream);

    int gb = (Ng + 63) / 64;
    k_gemm<CG,false><<<gb, 256, 0, stream>>>(g, nullptr, Wg, Yg, stats+0, stats+64, Ng);
    k_gemm<CS,true ><<<gb, 256, 0, stream>>>(x, down_idx, Ws, Ys, stats+128, stats+192, Ng);
    k_fuse<<<fb, 256, 0, stream>>>(Yg, Ys, stats, gamma_g, beta_g,
                                   gamma_s, beta_s, Wc, wbuf, wpart, Ng);
    int rb = (E + ECH - 1) / ECH;
    k_route<<<rb, 256, 0, stream>>>(pin, pout, wbuf, wpart, fb, gamma_c, beta_c,
                                    gcount, staging, E, P, NB, Ng);
    k_binacc<<<NB, 256, 0, stream>>>(gcount, staging, A, Nx);
    k_final<<<(Nx+63)/64, 256, 0, stream>>>(x, A, Winv, binv, (float*)d_out, Nx, K);
}